// Round 17
// baseline (44.057 us; speedup 1.0000x reference)
//
#include <hip/hip_runtime.h>
#include <math.h>

// Problem constants (from reference setup_inputs): B=32, N=256, D=32.
#define BB 32
#define NN 256
#define DD 32
#define TPB 256
// Blocks per batch: xx upper-tri (10) + yy upper-tri (10) + xy full (16).
#define BPB 36
#define NBLK (BB * BPB)          // 1152 = 18 groups x 64 blocks
#define NGRP 18
#define CNT_OFF 2048             // float index of counters in ws (byte 8192)

typedef short  bf16x8 __attribute__((ext_vector_type(8)));
typedef float  f32x4  __attribute__((ext_vector_type(4)));

__device__ __forceinline__ unsigned cvt_pk_bf16(float a, float b) {
    unsigned r;
    asm("v_cvt_pk_bf16_f32 %0, %1, %2" : "=v"(r) : "v"(a), "v"(b));
    return r;   // bits[15:0] = bf16(a), [31:16] = bf16(b)  (RNE; R13-verified)
}
__device__ __forceinline__ float fast_sqrt(float x) {
    float r;
    asm("v_sqrt_f32 %0, %1" : "=v"(r) : "v"(x));
    return r;
}
__device__ __forceinline__ float fast_exp2(float x) {
    float r;
    asm("v_exp_f32 %0, %1" : "=v"(r) : "v"(x));   // 2^x; input in [-0.36,0]
    return r;
}

// type 0: (x,x) | type 1: (y,y) | type 2: (x,y)
// Symmetric types compute only iq<=jq tiles; off-diag weighted 2x (bitwise-
// exact). Diagonal of xx/yy forced to sq=0. Fused finale with MODULAR
// counter election — works for ANY initial counter value (0xAA poison,
// stale values from prior replays), so no memset node is needed:
//   group (u32): 64 incs/call -> exactly one (og & 63)==63; 2^32%64==0 ->
//   wrap-safe. master (u64): 18 incs/call -> exactly one (om%18)==17.
// Finale reads all partials in fixed order in double -> deterministic value.
__global__ __launch_bounds__(TPB) void mmd_main(
    const float* __restrict__ x, const float* __restrict__ y,
    const float* __restrict__ w, float* __restrict__ ws,
    float* __restrict__ out) {
    float* partials = ws;                            // [0..NBLK)
    unsigned* gcnt = (unsigned*)(ws + CNT_OFF);      // 18 group counters
    unsigned long long* mcnt =
        (unsigned long long*)((char*)(ws + CNT_OFF) + 128);  // master (u64)

    const int blk = blockIdx.x;
    const int b   = blk / BPB;
    const int rem = blk - b * BPB;
    const int type = (rem >= 10) + (rem >= 20);
    int iq, jq;
    float weight;
    if (type == 2) {
        const int k = rem - 20;
        iq = k >> 2; jq = k & 3;
        weight = -2.0f;
    } else {
        const int k = rem - type * 10;
        iq = (k >= 4) + (k >= 7) + (k >= 9);
        jq = iq + k - ((9 * iq - iq * iq) >> 1);
        weight = (iq == jq) ? 1.0f : 2.0f;
    }
    const int tid  = threadIdx.x;
    const int wv   = tid >> 6;       // wave = one j-tile of 16
    const int lane = tid & 63;

    const float* Abase = (type == 1) ? y : x;
    const float* Bbase = (type == 0) ? x : y;
    const float* Aq = Abase + ((size_t)b * NN + iq * 64) * DD;  // 64 rows
    const float* Bq = Bbase + ((size_t)b * NN + jq * 64) * DD;  // 64 rows

    // LDS fragments [tile(4)][lane(64)]: lane l of tile t holds row
    // t*16+(l&15), k=(l>>4)*8..+7 (layout verified by R12 absmax=0).
    __shared__ bf16x8 Ah[4 * 64], Al[4 * 64], Bh[4 * 64], Bl[4 * 64];
    __shared__ float a2s[64], b2s[64];

    #pragma unroll
    for (int u = 0; u < 2; ++u) {
        const int e   = tid + u * 256;        // 0..511
        const int row = e >> 3;               // 0..63
        const int kq  = e & 7;                // float4 within row
        const int g   = kq >> 1;              // k-group of 8
        const int hw  = kq & 1;               // which uint2 half
        const int slot = (row >> 4) * 64 + g * 16 + (row & 15);
        {
            const float4 v = ((const float4*)Aq)[e];
            const unsigned h01 = cvt_pk_bf16(v.x, v.y);
            const unsigned h23 = cvt_pk_bf16(v.z, v.w);
            const float r0 = v.x - __uint_as_float(h01 << 16);
            const float r1 = v.y - __uint_as_float(h01 & 0xffff0000u);
            const float r2 = v.z - __uint_as_float(h23 << 16);
            const float r3 = v.w - __uint_as_float(h23 & 0xffff0000u);
            ((uint2*)&Ah[slot])[hw] = make_uint2(h01, h23);
            ((uint2*)&Al[slot])[hw] =
                make_uint2(cvt_pk_bf16(r0, r1), cvt_pk_bf16(r2, r3));
        }
        {
            const float4 v = ((const float4*)Bq)[e];
            const unsigned h01 = cvt_pk_bf16(v.x, v.y);
            const unsigned h23 = cvt_pk_bf16(v.z, v.w);
            const float r0 = v.x - __uint_as_float(h01 << 16);
            const float r1 = v.y - __uint_as_float(h01 & 0xffff0000u);
            const float r2 = v.z - __uint_as_float(h23 << 16);
            const float r3 = v.w - __uint_as_float(h23 & 0xffff0000u);
            ((uint2*)&Bh[slot])[hw] = make_uint2(h01, h23);
            ((uint2*)&Bl[slot])[hw] =
                make_uint2(cvt_pk_bf16(r0, r1), cvt_pk_bf16(r2, r3));
        }
    }
    // Per-row fp32 norms (rows L1-hot from staging).
    if (tid < 128) {
        const int r = tid & 63;
        const float4* rp = (const float4*)((tid < 64 ? Aq : Bq) + (size_t)r * DD);
        float c0 = 0.f, c1 = 0.f, c2 = 0.f, c3 = 0.f;
        #pragma unroll
        for (int k = 0; k < DD / 4; ++k) {
            float4 v = rp[k];
            c0 = fmaf(v.x, v.x, c0);
            c1 = fmaf(v.y, v.y, c1);
            c2 = fmaf(v.z, v.z, c2);
            c3 = fmaf(v.w, v.w, c3);
        }
        (tid < 64 ? a2s : b2s)[r] = (c0 + c1) + (c2 + c3);
    }
    __syncthreads();

    // Compute: wave owns j-tile wv, loops 4 i-tiles.
    const bf16x8 bh = Bh[wv * 64 + lane];
    const bf16x8 bl = Bl[wv * 64 + lane];
    const float  b2 = b2s[wv * 16 + (lane & 15)];
    // exp(negw*nrm) = 2^(negw*log2e*nrm)
    const float  negw2 = -w[b] * (1.0f / (float)DD) * 1.44269504088896f;
    const bool   sym = (type < 2) && (iq == jq);
    const int    rowbase = (lane >> 4) * 4;
    const int    colr = lane & 15;

    float acc = 0.f;
    #pragma unroll
    for (int it = 0; it < 4; ++it) {
        const bf16x8 ah = Ah[it * 64 + lane];
        const bf16x8 al = Al[it * 64 + lane];
        f32x4 c = {0.f, 0.f, 0.f, 0.f};
        c = __builtin_amdgcn_mfma_f32_16x16x32_bf16(al, bh, c, 0, 0, 0);
        c = __builtin_amdgcn_mfma_f32_16x16x32_bf16(ah, bl, c, 0, 0, 0);
        c = __builtin_amdgcn_mfma_f32_16x16x32_bf16(ah, bh, c, 0, 0, 0);
        const f32x4 a2q = *(const f32x4*)&a2s[it * 16 + rowbase];
        const bool diagt = sym && (it == wv);
        #pragma unroll
        for (int r = 0; r < 4; ++r) {
            float sq = fmaf(-2.0f, c[r], a2q[r] + b2);
            if (diagt && (rowbase + r == colr)) sq = 0.f;
            sq = fmaxf(sq, 1e-8f);   // folds norm clamp: sqrt(1e-8) = 1e-4
            acc += fast_exp2(negw2 * fast_sqrt(sq));
        }
    }

    // Deterministic block reduction: wave shuffle + fixed-order cross-wave.
    #pragma unroll
    for (int off = 32; off > 0; off >>= 1) acc += __shfl_down(acc, off, 64);
    __shared__ float red[4];
    if (lane == 0) red[wv] = acc;
    __syncthreads();

    // Publish partial; modular treed counters elect exactly one finale wave.
    unsigned flag_local = 0;
    if (tid == 0) {
        const float bsum = (red[0] + red[1]) + (red[2] + red[3]);
        const float scale = weight / ((float)NN * (float)NN * (float)BB);
        partials[blk] = bsum * scale;    // plain store
        __threadfence();                 // release: partial visible first
        const unsigned og = __hip_atomic_fetch_add(
            &gcnt[blk >> 6], 1u, __ATOMIC_ACQ_REL, __HIP_MEMORY_SCOPE_AGENT);
        if ((og & 63u) == 63u) {         // 64th arrival this call (any base)
            const unsigned long long om = __hip_atomic_fetch_add(
                mcnt, 1ull, __ATOMIC_ACQ_REL, __HIP_MEMORY_SCOPE_AGENT);
            flag_local = ((om % 18ull) == 17ull) ? 1u : 0u;  // 18th group
        }
    }
    if (tid < 64) {
        const unsigned f =
            (unsigned)__builtin_amdgcn_readfirstlane((int)flag_local);
        if (f) {
            __threadfence();             // acquire: see all partials
            double s = 0.0;
            #pragma unroll
            for (int t = 0; t < NBLK / 64; ++t) {      // fixed order: bitwise
                const float p = __hip_atomic_load(     // deterministic result
                    &partials[lane + t * 64],
                    __ATOMIC_RELAXED, __HIP_MEMORY_SCOPE_AGENT);
                s += (double)p;
            }
            #pragma unroll
            for (int off = 32; off > 0; off >>= 1)
                s += __shfl_down(s, off, 64);
            if (lane == 0) out[0] = (float)s;
        }
    }
}

extern "C" void kernel_launch(void* const* d_in, const int* in_sizes, int n_in,
                              void* d_out, int out_size, void* d_ws, size_t ws_size,
                              hipStream_t stream) {
    const float* x = (const float*)d_in[0];
    const float* y = (const float*)d_in[1];
    const float* w = (const float*)d_in[2];
    float* out = (float*)d_out;
    float* ws  = (float*)d_ws;   // [0..1152): partials; byte 8192+: counters

    // Single kernel node; counters need no reset (modular election works
    // from any initial value — R16 lesson: a memset node costs ~20us).
    mmd_main<<<NBLK, TPB, 0, stream>>>(x, y, w, ws, out);
}

// Round 18
// 17.040 us; speedup vs baseline: 2.5856x; 2.5856x over previous
//
#include <hip/hip_runtime.h>
#include <math.h>

// Problem constants (from reference setup_inputs): B=32, N=256, D=32.
#define BB 32
#define NN 256
#define DD 32
#define TPB 256
// 36 tile-jobs per batch (xx upper-tri 10 + yy upper-tri 10 + xy 16),
// 2 jobs per block -> 18 blocks/batch.
#define NBLK (BB * 18)           // 576 blocks
#define NPART (NBLK * 2)         // 1152 partials

typedef short  bf16x8 __attribute__((ext_vector_type(8)));
typedef float  f32x4  __attribute__((ext_vector_type(4)));

__device__ __forceinline__ unsigned cvt_pk_bf16(float a, float b) {
    unsigned r;
    asm("v_cvt_pk_bf16_f32 %0, %1, %2" : "=v"(r) : "v"(a), "v"(b));
    return r;   // bits[15:0] = bf16(a), [31:16] = bf16(b)  (RNE; R13-verified)
}
__device__ __forceinline__ float fast_sqrt(float x) {
    float r;
    asm("v_sqrt_f32 %0, %1" : "=v"(r) : "v"(x));
    return r;
}
__device__ __forceinline__ float fast_exp2(float x) {
    float r;
    asm("v_exp_f32 %0, %1" : "=v"(r) : "v"(x));   // 2^x; input in [-0.36,0]
    return r;
}

// type 0: (x,x) | type 1: (y,y) | type 2: (x,y)
// Two tile-jobs per block: all global loads for both jobs issue before ONE
// barrier (latency overlap), then both compute phases run back-to-back.
// Symmetric types compute only iq<=jq tiles; off-diag weighted 2x (bitwise-
// exact). Diagonal of xx/yy forced to sq=0. NO cross-block atomics/fences
// (R5/R16/R17 lesson: agent-scope fences cost ~30us on non-coherent XCD L2s).
__global__ __launch_bounds__(TPB) void mmd_main(
    const float* __restrict__ x, const float* __restrict__ y,
    const float* __restrict__ w, float* __restrict__ partials) {
    const int blk  = blockIdx.x;
    const int b    = blk / 18;
    const int r2   = blk - b * 18;
    const int tid  = threadIdx.x;
    const int wv   = tid >> 6;       // wave = one j-tile of 16
    const int lane = tid & 63;

    // Per-job geometry (wave-uniform scalars).
    int typeJ[2], iqJ[2], jqJ[2];
    float wtJ[2];
    const float* AqJ[2];
    const float* BqJ[2];
    #pragma unroll
    for (int j = 0; j < 2; ++j) {
        const int rem = r2 + j * 18;
        const int type = (rem >= 10) + (rem >= 20);
        int iq, jq;
        float weight;
        if (type == 2) {
            const int k = rem - 20;
            iq = k >> 2; jq = k & 3;
            weight = -2.0f;
        } else {
            const int k = rem - type * 10;
            iq = (k >= 4) + (k >= 7) + (k >= 9);
            jq = iq + k - ((9 * iq - iq * iq) >> 1);
            weight = (iq == jq) ? 1.0f : 2.0f;
        }
        typeJ[j] = type; iqJ[j] = iq; jqJ[j] = jq; wtJ[j] = weight;
        const float* Ab = (type == 1) ? y : x;
        const float* Bb = (type == 0) ? x : y;
        AqJ[j] = Ab + ((size_t)b * NN + iq * 64) * DD;
        BqJ[j] = Bb + ((size_t)b * NN + jq * 64) * DD;
    }

    // LDS fragments [job][tile(4)x64lane]: lane l of tile t holds row
    // t*16+(l&15), k=(l>>4)*8..+7 (layout verified by R12 absmax=0).
    __shared__ bf16x8 Ah[2][256], Al[2][256], Bh[2][256], Bl[2][256];
    __shared__ float a2s[2][64], b2s[2][64];
    __shared__ float red[2][4];

    #pragma unroll
    for (int j = 0; j < 2; ++j) {
        #pragma unroll
        for (int u = 0; u < 2; ++u) {
            const int e   = tid + u * 256;    // 0..511
            const int row = e >> 3;           // 0..63
            const int kq  = e & 7;            // float4 within row
            const int g   = kq >> 1;          // k-group of 8
            const int hw  = kq & 1;           // which uint2 half
            const int slot = (row >> 4) * 64 + g * 16 + (row & 15);
            {
                const float4 v = ((const float4*)AqJ[j])[e];
                const unsigned h01 = cvt_pk_bf16(v.x, v.y);
                const unsigned h23 = cvt_pk_bf16(v.z, v.w);
                const float r0 = v.x - __uint_as_float(h01 << 16);
                const float r1 = v.y - __uint_as_float(h01 & 0xffff0000u);
                const float r2_ = v.z - __uint_as_float(h23 << 16);
                const float r3 = v.w - __uint_as_float(h23 & 0xffff0000u);
                ((uint2*)&Ah[j][slot])[hw] = make_uint2(h01, h23);
                ((uint2*)&Al[j][slot])[hw] =
                    make_uint2(cvt_pk_bf16(r0, r1), cvt_pk_bf16(r2_, r3));
            }
            {
                const float4 v = ((const float4*)BqJ[j])[e];
                const unsigned h01 = cvt_pk_bf16(v.x, v.y);
                const unsigned h23 = cvt_pk_bf16(v.z, v.w);
                const float r0 = v.x - __uint_as_float(h01 << 16);
                const float r1 = v.y - __uint_as_float(h01 & 0xffff0000u);
                const float r2_ = v.z - __uint_as_float(h23 << 16);
                const float r3 = v.w - __uint_as_float(h23 & 0xffff0000u);
                ((uint2*)&Bh[j][slot])[hw] = make_uint2(h01, h23);
                ((uint2*)&Bl[j][slot])[hw] =
                    make_uint2(cvt_pk_bf16(r0, r1), cvt_pk_bf16(r2_, r3));
            }
        }
    }
    // Per-row fp32 norms — full-width now (2 jobs x 2 sides x 64 rows).
    {
        const int nj   = tid >> 7;            // job
        const int side = (tid >> 6) & 1;      // 0=A, 1=B
        const int r    = tid & 63;
        const float4* rp = (const float4*)(
            (side ? BqJ[nj] : AqJ[nj]) + (size_t)r * DD);
        float c0 = 0.f, c1 = 0.f, c2 = 0.f, c3 = 0.f;
        #pragma unroll
        for (int k = 0; k < DD / 4; ++k) {
            float4 v = rp[k];
            c0 = fmaf(v.x, v.x, c0);
            c1 = fmaf(v.y, v.y, c1);
            c2 = fmaf(v.z, v.z, c2);
            c3 = fmaf(v.w, v.w, c3);
        }
        (side ? b2s : a2s)[nj][r] = (c0 + c1) + (c2 + c3);
    }
    __syncthreads();

    // exp(negw*nrm) = 2^(negw*log2e*nrm)
    const float negw2 = -w[b] * (1.0f / (float)DD) * 1.44269504088896f;
    const int   rowbase = (lane >> 4) * 4;
    const int   colr = lane & 15;

    #pragma unroll
    for (int j = 0; j < 2; ++j) {
        const bf16x8 bh = Bh[j][wv * 64 + lane];
        const bf16x8 bl = Bl[j][wv * 64 + lane];
        const float  b2 = b2s[j][wv * 16 + (lane & 15)];
        const bool   sym = (typeJ[j] < 2) && (iqJ[j] == jqJ[j]);

        float acc = 0.f;
        #pragma unroll
        for (int it = 0; it < 4; ++it) {
            const bf16x8 ah = Ah[j][it * 64 + lane];
            const bf16x8 al = Al[j][it * 64 + lane];
            f32x4 c = {0.f, 0.f, 0.f, 0.f};
            c = __builtin_amdgcn_mfma_f32_16x16x32_bf16(al, bh, c, 0, 0, 0);
            c = __builtin_amdgcn_mfma_f32_16x16x32_bf16(ah, bl, c, 0, 0, 0);
            c = __builtin_amdgcn_mfma_f32_16x16x32_bf16(ah, bh, c, 0, 0, 0);
            const f32x4 a2q = *(const f32x4*)&a2s[j][it * 16 + rowbase];
            const bool diagt = sym && (it == wv);
            #pragma unroll
            for (int r = 0; r < 4; ++r) {
                float sq = fmaf(-2.0f, c[r], a2q[r] + b2);
                if (diagt && (rowbase + r == colr)) sq = 0.f;
                sq = fmaxf(sq, 1e-8f);  // folds norm clamp: sqrt(1e-8)=1e-4
                acc += fast_exp2(negw2 * fast_sqrt(sq));
            }
        }

        // Deterministic wave64 reduction for this job.
        #pragma unroll
        for (int off = 32; off > 0; off >>= 1)
            acc += __shfl_down(acc, off, 64);
        if (lane == 0) red[j][wv] = acc;
    }
    __syncthreads();
    if (tid == 0) {
        #pragma unroll
        for (int j = 0; j < 2; ++j) {
            const float bsum =
                (red[j][0] + red[j][1]) + (red[j][2] + red[j][3]);
            const float scale = wtJ[j] / ((float)NN * (float)NN * (float)BB);
            partials[blk + j * NBLK] = bsum * scale;
        }
    }
}

// Final deterministic reduction of NPART partials in double.
__global__ __launch_bounds__(256) void mmd_reduce(
    const float* __restrict__ partials, float* __restrict__ out) {
    double acc = 0.0;
    #pragma unroll
    for (int t = 0; t < 5; ++t) {
        const int idx = threadIdx.x + t * 256;
        if (idx < NPART) acc += (double)partials[idx];
    }
    #pragma unroll
    for (int off = 32; off > 0; off >>= 1) acc += __shfl_down(acc, off, 64);
    __shared__ double red[4];
    if ((threadIdx.x & 63) == 0) red[threadIdx.x >> 6] = acc;
    __syncthreads();
    if (threadIdx.x == 0)
        out[0] = (float)((red[0] + red[1]) + (red[2] + red[3]));
}

extern "C" void kernel_launch(void* const* d_in, const int* in_sizes, int n_in,
                              void* d_out, int out_size, void* d_ws, size_t ws_size,
                              hipStream_t stream) {
    const float* x = (const float*)d_in[0];
    const float* y = (const float*)d_in[1];
    const float* w = (const float*)d_in[2];
    float* out = (float*)d_out;
    float* partials = (float*)d_ws;  // NPART floats

    mmd_main<<<NBLK, TPB, 0, stream>>>(x, y, w, partials);
    mmd_reduce<<<1, 256, 0, stream>>>(partials, out);
}

// Round 19
// 12.320 us; speedup vs baseline: 3.5760x; 1.3831x over previous
//
#include <hip/hip_runtime.h>
#include <math.h>

// Problem constants (from reference setup_inputs): B=32, N=256, D=32.
#define BB 32
#define NN 256
#define DD 32
#define TPB 256
// Blocks per batch: xx upper-tri (10) + yy upper-tri (10) + xy full (16).
#define BPB 36
#define NBLK (BB * BPB)          // 1152
#define NPART NBLK

typedef short  bf16x8 __attribute__((ext_vector_type(8)));
typedef float  f32x4  __attribute__((ext_vector_type(4)));

__device__ __forceinline__ unsigned cvt_pk_bf16(float a, float b) {
    unsigned r;
    asm("v_cvt_pk_bf16_f32 %0, %1, %2" : "=v"(r) : "v"(a), "v"(b));
    return r;   // bits[15:0] = bf16(a), [31:16] = bf16(b)  (RNE; R13-verified)
}
__device__ __forceinline__ float fast_sqrt(float x) {
    float r;
    asm("v_sqrt_f32 %0, %1" : "=v"(r) : "v"(x));
    return r;
}
__device__ __forceinline__ float fast_exp2(float x) {
    float r;
    asm("v_exp_f32 %0, %1" : "=v"(r) : "v"(x));   // 2^x; input in [-0.36,0]
    return r;
}

// type 0: (x,x) | type 1: (y,y) | type 2: (x,y)
// Symmetric types compute only iq<=jq tiles; off-diagonal tiles weighted 2x
// (bitwise-exact: MFMA accumulation is A/B-symmetric, a2+b2 symmetric).
// Diagonal of xx/yy forced to sq=0 (exact clamp semantics, as in R12).
// Structure lessons (R13/R16/R17/R18): 2-node graph, one tile-job per
// block, no cross-block atomics/fences, no extra nodes.
__global__ __launch_bounds__(TPB) void mmd_main(
    const float* __restrict__ x, const float* __restrict__ y,
    const float* __restrict__ w, float* __restrict__ partials) {
    const int blk = blockIdx.x;
    const int b   = blk / BPB;
    const int rem = blk - b * BPB;
    const int type = (rem >= 10) + (rem >= 20);
    int iq, jq;
    float weight;
    if (type == 2) {
        const int k = rem - 20;
        iq = k >> 2; jq = k & 3;
        weight = -2.0f;
    } else {
        const int k = rem - type * 10;
        iq = (k >= 4) + (k >= 7) + (k >= 9);
        jq = iq + k - ((9 * iq - iq * iq) >> 1);
        weight = (iq == jq) ? 1.0f : 2.0f;
    }
    const int tid  = threadIdx.x;
    const int wv   = tid >> 6;       // wave = one j-tile of 16
    const int lane = tid & 63;

    const float* Abase = (type == 1) ? y : x;
    const float* Bbase = (type == 0) ? x : y;
    const float* Aq = Abase + ((size_t)b * NN + iq * 64) * DD;  // 64 rows
    const float* Bq = Bbase + ((size_t)b * NN + jq * 64) * DD;  // 64 rows

    // LDS fragments [tile(4)][lane(64)]: lane l of tile t holds row
    // t*16+(l&15), k=(l>>4)*8..+7 (layout verified by R12 absmax=0).
    __shared__ bf16x8 Ah[4 * 64], Al[4 * 64], Bh[4 * 64], Bl[4 * 64];
    __shared__ float a2s[64], b2s[64];

    #pragma unroll
    for (int u = 0; u < 2; ++u) {
        const int e   = tid + u * 256;        // 0..511
        const int row = e >> 3;               // 0..63
        const int kq  = e & 7;                // float4 within row
        const int g   = kq >> 1;              // k-group of 8
        const int hw  = kq & 1;               // which uint2 half
        const int slot = (row >> 4) * 64 + g * 16 + (row & 15);
        {
            const float4 v = ((const float4*)Aq)[e];
            const unsigned h01 = cvt_pk_bf16(v.x, v.y);
            const unsigned h23 = cvt_pk_bf16(v.z, v.w);
            const float r0 = v.x - __uint_as_float(h01 << 16);
            const float r1 = v.y - __uint_as_float(h01 & 0xffff0000u);
            const float r2 = v.z - __uint_as_float(h23 << 16);
            const float r3 = v.w - __uint_as_float(h23 & 0xffff0000u);
            ((uint2*)&Ah[slot])[hw] = make_uint2(h01, h23);
            ((uint2*)&Al[slot])[hw] =
                make_uint2(cvt_pk_bf16(r0, r1), cvt_pk_bf16(r2, r3));
        }
        {
            const float4 v = ((const float4*)Bq)[e];
            const unsigned h01 = cvt_pk_bf16(v.x, v.y);
            const unsigned h23 = cvt_pk_bf16(v.z, v.w);
            const float r0 = v.x - __uint_as_float(h01 << 16);
            const float r1 = v.y - __uint_as_float(h01 & 0xffff0000u);
            const float r2 = v.z - __uint_as_float(h23 << 16);
            const float r3 = v.w - __uint_as_float(h23 & 0xffff0000u);
            ((uint2*)&Bh[slot])[hw] = make_uint2(h01, h23);
            ((uint2*)&Bl[slot])[hw] =
                make_uint2(cvt_pk_bf16(r0, r1), cvt_pk_bf16(r2, r3));
        }
    }
    // Per-row fp32 norms (rows L1-hot from staging).
    if (tid < 128) {
        const int r = tid & 63;
        const float4* rp = (const float4*)((tid < 64 ? Aq : Bq) + (size_t)r * DD);
        float c0 = 0.f, c1 = 0.f, c2 = 0.f, c3 = 0.f;
        #pragma unroll
        for (int k = 0; k < DD / 4; ++k) {
            float4 v = rp[k];
            c0 = fmaf(v.x, v.x, c0);
            c1 = fmaf(v.y, v.y, c1);
            c2 = fmaf(v.z, v.z, c2);
            c3 = fmaf(v.w, v.w, c3);
        }
        (tid < 64 ? a2s : b2s)[r] = (c0 + c1) + (c2 + c3);
    }
    __syncthreads();

    // Compute: wave owns j-tile wv, loops 4 i-tiles.
    const bf16x8 bh = Bh[wv * 64 + lane];
    const bf16x8 bl = Bl[wv * 64 + lane];
    const float  b2 = b2s[wv * 16 + (lane & 15)];
    // exp(negw*nrm) = 2^(negw*log2e*nrm)
    const float  negw2 = -w[b] * (1.0f / (float)DD) * 1.44269504088896f;
    const bool   sym = (type < 2) && (iq == jq);
    const int    rowbase = (lane >> 4) * 4;
    const int    colr = lane & 15;

    float acc = 0.f;
    #pragma unroll
    for (int it = 0; it < 4; ++it) {
        const bf16x8 ah = Ah[it * 64 + lane];
        const bf16x8 al = Al[it * 64 + lane];
        f32x4 c = {0.f, 0.f, 0.f, 0.f};
        c = __builtin_amdgcn_mfma_f32_16x16x32_bf16(al, bh, c, 0, 0, 0);
        c = __builtin_amdgcn_mfma_f32_16x16x32_bf16(ah, bl, c, 0, 0, 0);
        c = __builtin_amdgcn_mfma_f32_16x16x32_bf16(ah, bh, c, 0, 0, 0);
        const f32x4 a2q = *(const f32x4*)&a2s[it * 16 + rowbase];
        const bool diagt = sym && (it == wv);
        #pragma unroll
        for (int r = 0; r < 4; ++r) {
            float sq = fmaf(-2.0f, c[r], a2q[r] + b2);
            if (diagt && (rowbase + r == colr)) sq = 0.f;
            sq = fmaxf(sq, 1e-8f);   // folds norm clamp: sqrt(1e-8) = 1e-4
            acc += fast_exp2(negw2 * fast_sqrt(sq));
        }
    }

    // Deterministic block reduction: wave shuffle + fixed-order cross-wave.
    #pragma unroll
    for (int off = 32; off > 0; off >>= 1) acc += __shfl_down(acc, off, 64);
    __shared__ float red[4];
    if (lane == 0) red[wv] = acc;
    __syncthreads();
    if (tid == 0) {
        const float bsum = (red[0] + red[1]) + (red[2] + red[3]);
        const float scale = weight / ((float)NN * (float)NN * (float)BB);
        partials[blk] = bsum * scale;
    }
}

// Final deterministic reduction of NPART partials in double.
__global__ __launch_bounds__(256) void mmd_reduce(
    const float* __restrict__ partials, float* __restrict__ out) {
    double acc = 0.0;
    #pragma unroll
    for (int t = 0; t < 5; ++t) {
        const int idx = threadIdx.x + t * 256;
        if (idx < NPART) acc += (double)partials[idx];
    }
    #pragma unroll
    for (int off = 32; off > 0; off >>= 1) acc += __shfl_down(acc, off, 64);
    __shared__ double red[4];
    if ((threadIdx.x & 63) == 0) red[threadIdx.x >> 6] = acc;
    __syncthreads();
    if (threadIdx.x == 0)
        out[0] = (float)((red[0] + red[1]) + (red[2] + red[3]));
}

extern "C" void kernel_launch(void* const* d_in, const int* in_sizes, int n_in,
                              void* d_out, int out_size, void* d_ws, size_t ws_size,
                              hipStream_t stream) {
    const float* x = (const float*)d_in[0];
    const float* y = (const float*)d_in[1];
    const float* w = (const float*)d_in[2];
    float* out = (float*)d_out;
    float* partials = (float*)d_ws;  // NPART floats

    mmd_main<<<NBLK, TPB, 0, stream>>>(x, y, w, partials);
    mmd_reduce<<<1, 256, 0, stream>>>(partials, out);
}